// Round 6
// baseline (152.735 us; speedup 1.0000x reference)
//
#include <hip/hip_runtime.h>
#include <hip/hip_bf16.h>

// Problem constants
#define NB   32      // batch
#define NC   24      // image channels
#define ND   12      // spatial
#define NN   144     // ND*ND objects
#define QD   11
#define GH   256
#define FOUT 10
#define MT2  162     // m-tiles per batch (20736 pairs / 128)

typedef unsigned short u16;
typedef __attribute__((ext_vector_type(8))) short bf16x8;
typedef __attribute__((ext_vector_type(4))) float f32x4;

// Workspace layout (u16 units unless noted):
//   Lqb  u16 [32][144][256]  off 0          (= L + q@Wg1_q + bg1, bf16)
//   Rb   u16 [32][144][256]  off 1179648
//   Bswz u16 [128][64][8]    off 2359296    (MFMA B-fragment order)
//   S    f32 [32][256]       byte-off 4849664
#define LQ_U16  0
#define R_U16   1179648
#define BS_U16  2359296
#define S_BYTE  4849664

__device__ inline float b2f(u16 v) {
  union { unsigned u; float f; } c; c.u = ((unsigned)v) << 16; return c.f;
}
__device__ inline u16 f2b(float f) {
  __hip_bfloat16 h = __float2bfloat16(f);
  return *reinterpret_cast<u16*>(&h);
}

// ---------------------------------------------------------------------------
// Fused prep:
//  blocks [0, 9216): per-object projections -> bf16 (Lq folds q-term + bg1).
//  blocks [9216, 9472): Wg2 -> bf16 B-fragment swizzle; zero S.
// ---------------------------------------------------------------------------
__global__ __launch_bounds__(256) void prep(const float* __restrict__ image,
                                            const float* __restrict__ question,
                                            const float* __restrict__ Wg1,
                                            const float* __restrict__ bg1,
                                            const float* __restrict__ Wg2,
                                            u16* __restrict__ Lq,
                                            u16* __restrict__ R,
                                            float* __restrict__ S,
                                            u16* __restrict__ Bswz) {
  int blk = blockIdx.x;
  int h   = threadIdx.x;
  if (blk < 2 * NB * NN) {
    int p     = blk % NN;
    int rest2 = blk / NN;
    int b     = rest2 & (NB - 1);
    int which = rest2 >> 5;
    const float* Wrow = Wg1 + which * (NC + 2) * GH;
    const float* img  = image + b * (NC * NN) + p;
    float acc = 0.f;
#pragma unroll
    for (int c = 0; c < NC; ++c) acc += img[c * NN] * Wrow[c * GH + h];
    int i = p / ND, j = p - i * ND;
    const float inv = 1.0f / (ND - 1);
    acc += (j * inv) * Wrow[24 * GH + h];
    acc += (i * inv) * Wrow[25 * GH + h];
    if (which == 0) {
      acc += bg1[h];
#pragma unroll
      for (int tq = 0; tq < QD; ++tq)
        acc += question[b * QD + tq] * Wg1[(2 * (NC + 2) + tq) * GH + h];
      Lq[(b * NN + p) * GH + h] = f2b(acc);
    } else {
      R[(b * NN + p) * GH + h] = f2b(acc);
    }
  } else {
    int tid = (blk - 2 * NB * NN) * 256 + h;   // 0..65535
    int e   = tid & 7;
    int l   = (tid >> 3) & 63;
    int fid = tid >> 9;
    int kt  = fid >> 4, nt = fid & 15;
    int k = kt * 32 + ((l >> 4) << 3) + e;
    int n = (nt << 4) + (l & 15);
    Bswz[tid] = f2b(Wg2[k * GH + n]);
    if (tid < NB * GH) S[tid] = 0.f;
  }
}

// ---------------------------------------------------------------------------
// MFMA pair GEMM v6. Block = 256 thr (4 waves), tile = 128 pairs x 256 cols.
// XCD-pinned grid: xcd = bid&7 owns batches [4*xcd, 4*xcd+4).
// Phase 1: build full 128x256 bf16 A-tile in LDS fragment layout (64 KB).
//   thread t: row t>>1, k-half t&1; 16 iters of {16B L + 16B R bf16 loads,
//   add+relu+cvt, ds_write_b128}. Write pattern: pos16&7 = row&7 -> 2-way
//   (free). ONE barrier.
// Phase 2: per wave, cols [64w, 64w+64), all 128 rows. 8 kt x
//   {8 ds_read_b128 A, 32 MFMA} with 2-deep B-fragment global prefetch.
//   No barriers.
// Epilogue: +bg2, relu, 32-row/lane sum, shfl 16/32 reduce, atomicAdd S[b,:].
// ---------------------------------------------------------------------------
__global__ __launch_bounds__(256, 2) void pair_gemm(const u16* __restrict__ Lq,
                                                    const u16* __restrict__ R,
                                                    const u16* __restrict__ Bswz,
                                                    const float* __restrict__ bg2,
                                                    float* __restrict__ S) {
  const int bid   = blockIdx.x;
  const int xcd   = bid & 7;
  const int g     = bid >> 3;             // 0..647
  const int b     = xcd * 4 + (g / MT2);  // batch
  const int mtile = g % MT2;
  const int p0    = mtile * 128;
  const int t     = threadIdx.x;
  const int w     = t >> 6;
  const int l     = t & 63;

  // [kt 8][mf 8][lane 64][8 bf16] = 64 KB
  __shared__ __align__(16) u16 As[8 * 8 * 64 * 8];

  // ---- Phase 1: build full A tile ----
  {
    const int row   = t >> 1;        // 0..127
    const int khalf = t & 1;         // which 128-k half
    const int p     = p0 + row;
    const int i     = p / NN;
    const int j     = p - i * NN;
    const u16* Lrow = Lq + (b * NN + i) * GH;
    const u16* Rrow = R + (b * NN + j) * GH;
    const int mf      = row >> 4;
    const int lane_lo = row & 15;
#pragma unroll
    for (int it = 0; it < 16; ++it) {
      const int ko = khalf * 16 + it;          // k-octet 0..31
      bf16x8 lv = *(const bf16x8*)(Lrow + ko * 8);
      bf16x8 rv = *(const bf16x8*)(Rrow + ko * 8);
      u16 o[8];
#pragma unroll
      for (int e = 0; e < 8; ++e) {
        float v = b2f((u16)lv[e]) + b2f((u16)rv[e]);
        o[e] = f2b(v > 0.f ? v : 0.f);
      }
      const int kt    = ko >> 2;
      const int pos16 = (((kt << 3) | mf) << 6) | lane_lo | ((ko & 3) << 4);
      *(bf16x8*)&As[pos16 << 3] = *(bf16x8*)o;
    }
  }
  __syncthreads();

  // ---- Phase 2: MFMA stream with 2-deep B prefetch ----
  const u16* Bl = Bswz + l * 8;
  f32x4 acc[8][4] = {};
  bf16x8 bcur[4], bnxt[4];
#pragma unroll
  for (int ntl = 0; ntl < 4; ++ntl)
    bcur[ntl] = *(const bf16x8*)(Bl + ((size_t)((w << 2) | ntl) << 9));
#pragma unroll
  for (int kt = 0; kt < 8; ++kt) {
    if (kt < 7) {
#pragma unroll
      for (int ntl = 0; ntl < 4; ++ntl) {
        int fid = ((kt + 1) << 4) | (w << 2) | ntl;
        bnxt[ntl] = *(const bf16x8*)(Bl + ((size_t)fid << 9));
      }
    }
    bf16x8 af[8];
#pragma unroll
    for (int mf = 0; mf < 8; ++mf)
      af[mf] = *(const bf16x8*)&As[((((kt << 3) | mf) << 6) | l) << 3];
#pragma unroll
    for (int mf = 0; mf < 8; ++mf)
#pragma unroll
      for (int ntl = 0; ntl < 4; ++ntl)
        acc[mf][ntl] = __builtin_amdgcn_mfma_f32_16x16x32_bf16(
            af[mf], bcur[ntl], acc[mf][ntl], 0, 0, 0);
#pragma unroll
    for (int ntl = 0; ntl < 4; ++ntl) bcur[ntl] = bnxt[ntl];
  }

  // Epilogue: C/D layout col = l&15, row = (l>>4)*4 + reg.
  float* Sb = S + b * GH;
#pragma unroll
  for (int ntl = 0; ntl < 4; ++ntl) {
    int n = (w << 6) + (ntl << 4) + (l & 15);
    float bgv = bg2[n];
    float s = 0.f;
#pragma unroll
    for (int mf = 0; mf < 8; ++mf)
#pragma unroll
      for (int r = 0; r < 4; ++r) {
        float v = acc[mf][ntl][r] + bgv;
        s += v > 0.f ? v : 0.f;
      }
    s += __shfl_xor(s, 16, 64);
    s += __shfl_xor(s, 32, 64);
    if (l < 16) atomicAdd(&Sb[n], s);
  }
}

// ---------------------------------------------------------------------------
// Final f-MLP: out = relu(S@Wf1+bf1)@Wf2+bf2. One block per batch.
// ---------------------------------------------------------------------------
__global__ __launch_bounds__(256) void final_mlp(const float* __restrict__ S,
                                                 const float* __restrict__ Wf1,
                                                 const float* __restrict__ bf1,
                                                 const float* __restrict__ Wf2,
                                                 const float* __restrict__ bf2,
                                                 float* __restrict__ out) {
  __shared__ float sS[GH];
  __shared__ float oS[GH];
  int b = blockIdx.x, h = threadIdx.x;
  sS[h] = S[b * GH + h];
  __syncthreads();
  float acc = bf1[h];
#pragma unroll 8
  for (int k = 0; k < GH; ++k) acc += sS[k] * Wf1[k * GH + h];
  oS[h] = acc > 0.f ? acc : 0.f;
  __syncthreads();
  if (h < FOUT) {
    float o = bf2[h];
#pragma unroll 8
    for (int k = 0; k < GH; ++k) o += oS[k] * Wf2[k * FOUT + h];
    out[b * FOUT + h] = o;
  }
}

extern "C" void kernel_launch(void* const* d_in, const int* in_sizes, int n_in,
                              void* d_out, int out_size, void* d_ws, size_t ws_size,
                              hipStream_t stream) {
  const float* image    = (const float*)d_in[0];
  const float* question = (const float*)d_in[1];
  const float* Wg1      = (const float*)d_in[2];
  const float* bg1      = (const float*)d_in[3];
  const float* Wg2      = (const float*)d_in[4];
  const float* bg2      = (const float*)d_in[5];
  const float* Wf1      = (const float*)d_in[6];
  const float* bf1      = (const float*)d_in[7];
  const float* Wf2      = (const float*)d_in[8];
  const float* bf2      = (const float*)d_in[9];
  float* out = (float*)d_out;

  u16*   wsb  = (u16*)d_ws;
  u16*   Lqp  = wsb + LQ_U16;
  u16*   Rp   = wsb + R_U16;
  u16*   Bswz = wsb + BS_U16;
  float* Sp   = (float*)((char*)d_ws + S_BYTE);

  prep<<<2 * NB * NN + 256, 256, 0, stream>>>(image, question, Wg1, bg1, Wg2,
                                              Lqp, Rp, Sp, Bswz);
  pair_gemm<<<NB * MT2, 256, 0, stream>>>(Lqp, Rp, Bswz, bg2, Sp);
  final_mlp<<<NB, 256, 0, stream>>>(Sp, Wf1, bf1, Wf2, bf2, out);
}

// Round 7
// 141.140 us; speedup vs baseline: 1.0822x; 1.0822x over previous
//
#include <hip/hip_runtime.h>
#include <hip/hip_bf16.h>

// Problem constants
#define NB   32      // batch
#define NC   24      // image channels
#define ND   12      // spatial
#define NN   144     // ND*ND objects
#define QD   11
#define GH   256
#define FOUT 10
#define NTILE 324    // 64-row m-tiles per batch
#define BPB  16      // blocks per batch (512 total = 2/CU)

typedef unsigned short u16;
typedef __attribute__((ext_vector_type(8))) short bf16x8;
typedef __attribute__((ext_vector_type(4))) float f32x4;

// Workspace layout (u16 units unless noted):
//   Lqb  u16 [32][144][256]  off 0          (= L + q@Wg1_q + bg1, bf16)
//   Rb   u16 [32][144][256]  off 1179648
//   Bswz u16 [128][64][8]    off 2359296    (MFMA B-fragment order)
//   S    f32 [32][256]       byte-off 4849664
#define LQ_U16  0
#define R_U16   1179648
#define BS_U16  2359296
#define S_BYTE  4849664

__device__ inline float b2f(u16 v) {
  union { unsigned u; float f; } c; c.u = ((unsigned)v) << 16; return c.f;
}
__device__ inline u16 f2b(float f) {
  __hip_bfloat16 h = __float2bfloat16(f);
  return *reinterpret_cast<u16*>(&h);
}

// ---------------------------------------------------------------------------
// Fused prep:
//  blocks [0, 9216): per-object projections -> bf16 (Lq folds q-term + bg1).
//  blocks [9216, 9472): Wg2 -> bf16 B-fragment swizzle; zero S.
// ---------------------------------------------------------------------------
__global__ __launch_bounds__(256) void prep(const float* __restrict__ image,
                                            const float* __restrict__ question,
                                            const float* __restrict__ Wg1,
                                            const float* __restrict__ bg1,
                                            const float* __restrict__ Wg2,
                                            u16* __restrict__ Lq,
                                            u16* __restrict__ R,
                                            float* __restrict__ S,
                                            u16* __restrict__ Bswz) {
  int blk = blockIdx.x;
  int h   = threadIdx.x;
  if (blk < 2 * NB * NN) {
    int p     = blk % NN;
    int rest2 = blk / NN;
    int b     = rest2 & (NB - 1);
    int which = rest2 >> 5;
    const float* Wrow = Wg1 + which * (NC + 2) * GH;
    const float* img  = image + b * (NC * NN) + p;
    float acc = 0.f;
#pragma unroll
    for (int c = 0; c < NC; ++c) acc += img[c * NN] * Wrow[c * GH + h];
    int i = p / ND, j = p - i * ND;
    const float inv = 1.0f / (ND - 1);
    acc += (j * inv) * Wrow[24 * GH + h];
    acc += (i * inv) * Wrow[25 * GH + h];
    if (which == 0) {
      acc += bg1[h];
#pragma unroll
      for (int tq = 0; tq < QD; ++tq)
        acc += question[b * QD + tq] * Wg1[(2 * (NC + 2) + tq) * GH + h];
      Lq[(b * NN + p) * GH + h] = f2b(acc);
    } else {
      R[(b * NN + p) * GH + h] = f2b(acc);
    }
  } else {
    int tid = (blk - 2 * NB * NN) * 256 + h;   // 0..65535
    int e   = tid & 7;
    int l   = (tid >> 3) & 63;
    int fid = tid >> 9;
    int kt  = fid >> 4, nt = fid & 15;
    int k = kt * 32 + ((l >> 4) << 3) + e;
    int n = (nt << 4) + (l & 15);
    Bswz[tid] = f2b(Wg2[k * GH + n]);
    if (tid < NB * GH) S[tid] = 0.f;
  }
}

// ---------------------------------------------------------------------------
// MFMA pair GEMM v7: persistent multi-tile blocks with tile-level
// double-buffered LDS; build of tile t+1 interleaved into the MFMA stream of
// tile t (VALU and matrix pipes overlap). One barrier per tile.
// Block = 256 thr (4 waves); tile = 64 pairs x 256 cols; block runs 20-21
// consecutive tiles. Grid = 512 blocks = exactly 2/CU; XCD-pinned batches.
// L/R loads: 2-deep register ring. B-frags: 1-deep ring (tile-invariant).
// Epilogue folds relu(acc+bg2) into running per-thread sums; atomics once.
// ---------------------------------------------------------------------------
__global__ __launch_bounds__(256, 2) void pair_gemm(const u16* __restrict__ Lq,
                                                    const u16* __restrict__ R,
                                                    const u16* __restrict__ Bswz,
                                                    const float* __restrict__ bg2,
                                                    float* __restrict__ S) {
  const int bid = blockIdx.x;          // 0..511
  const int xcd = bid & 7;
  const int idx = bid >> 3;            // 0..63
  const int b   = xcd * 4 + (idx >> 4);
  const int bi  = idx & 15;
  const int t0  = bi * 20 + (bi < 4 ? bi : 4);   // 4 blocks get 21 tiles, 12 get 20
  const int cnt = 20 + (bi < 4 ? 1 : 0);

  __shared__ __align__(16) u16 As[2][16384];     // 2 x 32 KB, fragment layout

  const int t = threadIdx.x;
  const int w = t >> 6, l = t & 63;
  const int brow = t >> 2, c = t & 3;            // build role: row, k-octet
  const int mf_w = brow >> 4;
  const int lane_w = (brow & 15) | (c << 4);
  const int woff16 = (mf_w << 6) | lane_w;       // + (q<<8) per kt-group

  const u16* Lbase = Lq + b * NN * GH;
  const u16* Rbase = R + b * NN * GH;
  const u16* Bl    = Bswz + l * 8;

  float bgv[4];
#pragma unroll
  for (int ntl = 0; ntl < 4; ++ntl)
    bgv[ntl] = bg2[(w << 6) + (ntl << 4) + (l & 15)];

  float ssum[4] = {0.f, 0.f, 0.f, 0.f};

  // Prologue: build tile t0 fully into As[0]
  {
    int p = t0 * 64 + brow;
    int i = p / NN, j = p - i * NN;
    const u16* Lr = Lbase + i * GH + c * 8;
    const u16* Rr = Rbase + j * GH + c * 8;
#pragma unroll
    for (int q = 0; q < 8; ++q) {
      bf16x8 lv = *(const bf16x8*)(Lr + q * 32);
      bf16x8 rv = *(const bf16x8*)(Rr + q * 32);
      u16 o[8];
#pragma unroll
      for (int e = 0; e < 8; ++e) {
        float v = b2f((u16)lv[e]) + b2f((u16)rv[e]);
        o[e] = f2b(v > 0.f ? v : 0.f);
      }
      *(bf16x8*)&As[0][((q << 8) | woff16) << 3] = *(bf16x8*)o;
    }
  }

  // Build-tile (t0+1) row pointers + prime 2-deep L/R ring
  const u16* Lb_p = Lbase;  const u16* Rb_p = Rbase;
  const u16* Ll_p = Lbase;  const u16* Rl_p = Rbase;
  bf16x8 ringL[2], ringR[2];
  if (cnt > 1) {
    int p = (t0 + 1) * 64 + brow;
    int i = p / NN, j = p - i * NN;
    Lb_p = Lbase + i * GH + c * 8;
    Rb_p = Rbase + j * GH + c * 8;
    ringL[0] = *(const bf16x8*)(Lb_p);
    ringR[0] = *(const bf16x8*)(Rb_p);
    ringL[1] = *(const bf16x8*)(Lb_p + 32);
    ringR[1] = *(const bf16x8*)(Rb_p + 32);
  }
  __syncthreads();

  // B ring: prefetch group 0
  bf16x8 bcur[4], bnxt[4];
#pragma unroll
  for (int ntl = 0; ntl < 4; ++ntl)
    bcur[ntl] = *(const bf16x8*)(Bl + ((size_t)((w << 2) | ntl) << 9));

  for (int tt = 0; tt < cnt; ++tt) {
    const int  cur = tt & 1;
    const bool hb  = (tt + 1 < cnt);
    f32x4 acc[4][4] = {};
#pragma unroll
    for (int q = 0; q < 8; ++q) {
      // B prefetch for next group (wraps to group 0 for the next tile)
#pragma unroll
      for (int ntl = 0; ntl < 4; ++ntl) {
        int fid = (((q + 1) & 7) << 4) | (w << 2) | ntl;
        bnxt[ntl] = *(const bf16x8*)(Bl + ((size_t)fid << 9));
      }
      // A fragments for this group
      bf16x8 af[4];
#pragma unroll
      for (int mf = 0; mf < 4; ++mf)
        af[mf] = *(const bf16x8*)&As[cur][((((q << 2) | mf) << 6) | l) << 3];
      // build step q of tile tt+1 into the other buffer (VALU, overlaps MFMA)
      if (hb) {
        bf16x8 lv = ringL[q & 1], rv = ringR[q & 1];
        u16 o[8];
#pragma unroll
        for (int e = 0; e < 8; ++e) {
          float v = b2f((u16)lv[e]) + b2f((u16)rv[e]);
          o[e] = f2b(v > 0.f ? v : 0.f);
        }
        *(bf16x8*)&As[cur ^ 1][((q << 8) | woff16) << 3] = *(bf16x8*)o;
        // issue loads for build step q+2 (2-deep ring; crosses into tile tt+2)
        if (q < 6) {
          ringL[q & 1] = *(const bf16x8*)(Lb_p + (q + 2) * 32);
          ringR[q & 1] = *(const bf16x8*)(Rb_p + (q + 2) * 32);
        } else if (tt + 2 < cnt) {
          if (q == 6) {
            int p = (t0 + tt + 2) * 64 + brow;
            int i = p / NN, j = p - i * NN;
            Ll_p = Lbase + i * GH + c * 8;
            Rl_p = Rbase + j * GH + c * 8;
          }
          ringL[q & 1] = *(const bf16x8*)(Ll_p + (q - 6) * 32);
          ringR[q & 1] = *(const bf16x8*)(Rl_p + (q - 6) * 32);
        }
      }
      // MFMA group: 16 MFMAs
#pragma unroll
      for (int mf = 0; mf < 4; ++mf)
#pragma unroll
        for (int ntl = 0; ntl < 4; ++ntl)
          acc[mf][ntl] = __builtin_amdgcn_mfma_f32_16x16x32_bf16(
              af[mf], bcur[ntl], acc[mf][ntl], 0, 0, 0);
#pragma unroll
      for (int ntl = 0; ntl < 4; ++ntl) bcur[ntl] = bnxt[ntl];
    }
    // advance build-tile pointers (computed at q==6)
    Lb_p = Ll_p; Rb_p = Rl_p;
    // per-tile epilogue: fold relu(acc + bg2) into running sums
#pragma unroll
    for (int ntl = 0; ntl < 4; ++ntl) {
      float s = 0.f;
#pragma unroll
      for (int mf = 0; mf < 4; ++mf)
#pragma unroll
        for (int r = 0; r < 4; ++r) {
          float v = acc[mf][ntl][r] + bgv[ntl];
          s += v > 0.f ? v : 0.f;
        }
      ssum[ntl] += s;
    }
    __syncthreads();
  }

  // Final reduce: C/D col = l&15; sum rows via shfl, one atomic per col slice
  float* Sb = S + b * GH;
#pragma unroll
  for (int ntl = 0; ntl < 4; ++ntl) {
    float s = ssum[ntl];
    s += __shfl_xor(s, 16, 64);
    s += __shfl_xor(s, 32, 64);
    if (l < 16) atomicAdd(&Sb[(w << 6) + (ntl << 4) + (l & 15)], s);
  }
}

// ---------------------------------------------------------------------------
// Final f-MLP: out = relu(S@Wf1+bf1)@Wf2+bf2. One block per batch.
// ---------------------------------------------------------------------------
__global__ __launch_bounds__(256) void final_mlp(const float* __restrict__ S,
                                                 const float* __restrict__ Wf1,
                                                 const float* __restrict__ bf1,
                                                 const float* __restrict__ Wf2,
                                                 const float* __restrict__ bf2,
                                                 float* __restrict__ out) {
  __shared__ float sS[GH];
  __shared__ float oS[GH];
  int b = blockIdx.x, h = threadIdx.x;
  sS[h] = S[b * GH + h];
  __syncthreads();
  float acc = bf1[h];
#pragma unroll 8
  for (int k = 0; k < GH; ++k) acc += sS[k] * Wf1[k * GH + h];
  oS[h] = acc > 0.f ? acc : 0.f;
  __syncthreads();
  if (h < FOUT) {
    float o = bf2[h];
#pragma unroll 8
    for (int k = 0; k < GH; ++k) o += oS[k] * Wf2[k * FOUT + h];
    out[b * FOUT + h] = o;
  }
}

extern "C" void kernel_launch(void* const* d_in, const int* in_sizes, int n_in,
                              void* d_out, int out_size, void* d_ws, size_t ws_size,
                              hipStream_t stream) {
  const float* image    = (const float*)d_in[0];
  const float* question = (const float*)d_in[1];
  const float* Wg1      = (const float*)d_in[2];
  const float* bg1      = (const float*)d_in[3];
  const float* Wg2      = (const float*)d_in[4];
  const float* bg2      = (const float*)d_in[5];
  const float* Wf1      = (const float*)d_in[6];
  const float* bf1      = (const float*)d_in[7];
  const float* Wf2      = (const float*)d_in[8];
  const float* bf2      = (const float*)d_in[9];
  float* out = (float*)d_out;

  u16*   wsb  = (u16*)d_ws;
  u16*   Lqp  = wsb + LQ_U16;
  u16*   Rp   = wsb + R_U16;
  u16*   Bswz = wsb + BS_U16;
  float* Sp   = (float*)((char*)d_ws + S_BYTE);

  prep<<<2 * NB * NN + 256, 256, 0, stream>>>(image, question, Wg1, bg1, Wg2,
                                              Lqp, Rp, Sp, Bswz);
  pair_gemm<<<NB * BPB, 256, 0, stream>>>(Lqp, Rp, Bswz, bg2, Sp);
  final_mlp<<<NB, 256, 0, stream>>>(Sp, Wf1, bf1, Wf2, bf2, out);
}

// Round 8
// 140.791 us; speedup vs baseline: 1.0848x; 1.0025x over previous
//
#include <hip/hip_runtime.h>
#include <hip/hip_bf16.h>

// Problem constants
#define NB   32      // batch
#define NC   24      // image channels
#define ND   12      // spatial
#define NN   144     // ND*ND objects
#define QD   11
#define GH   256
#define FOUT 10
#define BPB  16      // blocks per batch (512 total = 2/CU)

typedef unsigned short u16;
typedef __attribute__((ext_vector_type(8))) short bf16x8;
typedef __attribute__((ext_vector_type(4))) float f32x4;

// Workspace layout:
//   Lq  f32 [32][144][256]  float-off 0         (= L + q@Wg1_q + bg1 folded)
//   R   f32 [32][144][256]  float-off 1179648
//   S   f32 [32][256]       float-off 2359296
//   Bswz u16 [128][64][8]   u16-off  4734976    (MFMA B-fragment order)
#define LQ_OFF  0
#define R_OFF   1179648
#define S_OFF   2359296
#define BS_U16  4734976

__device__ inline u16 f2b(float f) {
  __hip_bfloat16 h = __float2bfloat16(f);
  return *reinterpret_cast<u16*>(&h);
}

// ---------------------------------------------------------------------------
// Fused prep (f32 Lq/R):
//  blocks [0, 9216): per-object projections (Lq folds q-term + bg1).
//  blocks [9216, 9472): Wg2 -> bf16 B-fragment swizzle; zero S.
// ---------------------------------------------------------------------------
__global__ __launch_bounds__(256) void prep(const float* __restrict__ image,
                                            const float* __restrict__ question,
                                            const float* __restrict__ Wg1,
                                            const float* __restrict__ bg1,
                                            const float* __restrict__ Wg2,
                                            float* __restrict__ Lq,
                                            float* __restrict__ R,
                                            float* __restrict__ S,
                                            u16* __restrict__ Bswz) {
  int blk = blockIdx.x;
  int h   = threadIdx.x;
  if (blk < 2 * NB * NN) {
    int p     = blk % NN;
    int rest2 = blk / NN;
    int b     = rest2 & (NB - 1);
    int which = rest2 >> 5;
    const float* Wrow = Wg1 + which * (NC + 2) * GH;
    const float* img  = image + b * (NC * NN) + p;
    float acc = 0.f;
#pragma unroll
    for (int c = 0; c < NC; ++c) acc += img[c * NN] * Wrow[c * GH + h];
    int i = p / ND, j = p - i * ND;
    const float inv = 1.0f / (ND - 1);
    acc += (j * inv) * Wrow[24 * GH + h];
    acc += (i * inv) * Wrow[25 * GH + h];
    if (which == 0) {
      acc += bg1[h];
#pragma unroll
      for (int tq = 0; tq < QD; ++tq)
        acc += question[b * QD + tq] * Wg1[(2 * (NC + 2) + tq) * GH + h];
      Lq[(b * NN + p) * GH + h] = acc;
    } else {
      R[(b * NN + p) * GH + h] = acc;
    }
  } else {
    int tid = (blk - 2 * NB * NN) * 256 + h;   // 0..65535
    int e   = tid & 7;
    int l   = (tid >> 3) & 63;
    int fid = tid >> 9;
    int kt  = fid >> 4, nt = fid & 15;
    int k = kt * 32 + ((l >> 4) << 3) + e;
    int n = (nt << 4) + (l & 15);
    Bswz[tid] = f2b(Wg2[k * GH + n]);
    if (tid < NB * GH) S[tid] = 0.f;
  }
}

// ---------------------------------------------------------------------------
// MFMA pair GEMM v8: persistent blocks, tile-level double-buffered LDS, build
// of tile t+1 interleaved into the MFMA stream of tile t. ONE barrier/tile.
// Lean registers: no explicit prefetch rings (compiler schedules); f32 build
// (add+max+cvt only); XOR-swizzled ds_write lanes (2-way, free).
// Block = 256 thr (4 waves), tile = 64 pairs x 256 cols, ~20 tiles/block.
// Grid = 512 blocks (2/CU), XCD-pinned batches.
// ---------------------------------------------------------------------------
__global__ __launch_bounds__(256, 2) void pair_gemm(const float* __restrict__ Lq,
                                                    const float* __restrict__ R,
                                                    const u16* __restrict__ Bswz,
                                                    const float* __restrict__ bg2,
                                                    float* __restrict__ S) {
  const int bid = blockIdx.x;          // 0..511
  const int xcd = bid & 7;
  const int idx = bid >> 3;            // 0..63
  const int b   = xcd * 4 + (idx >> 4);
  const int bi  = idx & 15;
  const int t0  = bi * 20 + (bi < 4 ? bi : 4);   // 4 blocks: 21 tiles, 12: 20
  const int cnt = 20 + (bi < 4 ? 1 : 0);

  __shared__ __align__(16) u16 As[2][16384];     // 2 x 32 KB fragment layout

  const int t = threadIdx.x;
  const int w = t >> 6, l = t & 63;
  const int brow = t >> 2, c = t & 3;            // build role: row, k-octet
  // store: frag f=(q<<2)|(brow>>4), frag-lane x=(brow&15)|(c<<4),
  // swizzled unit = (f<<6) | (x ^ (c<<1))  -> 2-way banked (free)
  const int lane_w = ((brow & 15) | (c << 4)) ^ (c << 1);
  const int mf_w   = brow >> 4;
  // consumer reads unit (f<<6) | (l ^ (((l>>4)&3)<<1))
  const int lane_r = l ^ (((l >> 4) & 3) << 1);

  const float* Lbase = Lq + b * NN * GH;
  const float* Rbase = R + b * NN * GH;
  const u16*   Bl    = Bswz + l * 8;

  float bgv[4];
#pragma unroll
  for (int ntl = 0; ntl < 4; ++ntl)
    bgv[ntl] = bg2[(w << 6) + (ntl << 4) + (l & 15)];
  float ssum[4] = {0.f, 0.f, 0.f, 0.f};

  // Prologue: build tile t0 fully into As[0]
  {
    int p = t0 * 64 + brow;
    int i = p / NN, j = p - i * NN;
    const float* Lr = Lbase + i * GH + c * 8;
    const float* Rr = Rbase + j * GH + c * 8;
#pragma unroll
    for (int q = 0; q < 8; ++q) {
      float lv[8], rv[8];
      *(float4*)&lv[0] = *(const float4*)(Lr + q * 32);
      *(float4*)&lv[4] = *(const float4*)(Lr + q * 32 + 4);
      *(float4*)&rv[0] = *(const float4*)(Rr + q * 32);
      *(float4*)&rv[4] = *(const float4*)(Rr + q * 32 + 4);
      u16 o[8];
#pragma unroll
      for (int e = 0; e < 8; ++e) {
        float v = lv[e] + rv[e];
        o[e] = f2b(v > 0.f ? v : 0.f);
      }
      *(bf16x8*)&As[0][((((q << 2) | mf_w) << 6) | lane_w) << 3] = *(bf16x8*)o;
    }
  }
  __syncthreads();

  for (int tt = 0; tt < cnt; ++tt) {
    const int  cur = tt & 1;
    const bool hb  = (tt + 1 < cnt);
    // build-tile row pointers (cheap per-tile recompute)
    const float* Lb = Lbase;
    const float* Rb = Rbase;
    if (hb) {
      int p = (t0 + tt + 1) * 64 + brow;
      int i = p / NN, j = p - i * NN;
      Lb = Lbase + i * GH + c * 8;
      Rb = Rbase + j * GH + c * 8;
    }
    f32x4 acc[4][4] = {};
#pragma unroll
    for (int q = 0; q < 8; ++q) {
      // A fragments for this group (swizzle-read)
      bf16x8 af[4];
#pragma unroll
      for (int mf = 0; mf < 4; ++mf)
        af[mf] = *(const bf16x8*)&As[cur][((((q << 2) | mf) << 6) | lane_r) << 3];
      // B fragments (L2-resident)
      bf16x8 bfr[4];
#pragma unroll
      for (int ntl = 0; ntl < 4; ++ntl) {
        int fid = (q << 4) | (w << 2) | ntl;
        bfr[ntl] = *(const bf16x8*)(Bl + ((size_t)fid << 9));
      }
      // interleaved build of tile tt+1, octet q (VALU; overlaps MFMA pipe)
      if (hb) {
        float lv[8], rv[8];
        *(float4*)&lv[0] = *(const float4*)(Lb + q * 32);
        *(float4*)&lv[4] = *(const float4*)(Lb + q * 32 + 4);
        *(float4*)&rv[0] = *(const float4*)(Rb + q * 32);
        *(float4*)&rv[4] = *(const float4*)(Rb + q * 32 + 4);
        u16 o[8];
#pragma unroll
        for (int e = 0; e < 8; ++e) {
          float v = lv[e] + rv[e];
          o[e] = f2b(v > 0.f ? v : 0.f);
        }
        *(bf16x8*)&As[cur ^ 1][((((q << 2) | mf_w) << 6) | lane_w) << 3] =
            *(bf16x8*)o;
      }
      // 16 MFMAs
#pragma unroll
      for (int mf = 0; mf < 4; ++mf)
#pragma unroll
        for (int ntl = 0; ntl < 4; ++ntl)
          acc[mf][ntl] = __builtin_amdgcn_mfma_f32_16x16x32_bf16(
              af[mf], bfr[ntl], acc[mf][ntl], 0, 0, 0);
    }
    // per-tile epilogue: fold relu(acc + bg2) into running sums
#pragma unroll
    for (int ntl = 0; ntl < 4; ++ntl) {
      float s = 0.f;
#pragma unroll
      for (int mf = 0; mf < 4; ++mf)
#pragma unroll
        for (int r = 0; r < 4; ++r) {
          float v = acc[mf][ntl][r] + bgv[ntl];
          s += v > 0.f ? v : 0.f;
        }
      ssum[ntl] += s;
    }
    __syncthreads();
  }

  // Final reduce: C/D col = l&15; shfl-reduce rows, one atomic per col slice
  float* Sb = S + b * GH;
#pragma unroll
  for (int ntl = 0; ntl < 4; ++ntl) {
    float s = ssum[ntl];
    s += __shfl_xor(s, 16, 64);
    s += __shfl_xor(s, 32, 64);
    if (l < 16) atomicAdd(&Sb[(w << 6) + (ntl << 4) + (l & 15)], s);
  }
}

// ---------------------------------------------------------------------------
// Final f-MLP: out = relu(S@Wf1+bf1)@Wf2+bf2. One block per batch.
// ---------------------------------------------------------------------------
__global__ __launch_bounds__(256) void final_mlp(const float* __restrict__ S,
                                                 const float* __restrict__ Wf1,
                                                 const float* __restrict__ bf1,
                                                 const float* __restrict__ Wf2,
                                                 const float* __restrict__ bf2,
                                                 float* __restrict__ out) {
  __shared__ float sS[GH];
  __shared__ float oS[GH];
  int b = blockIdx.x, h = threadIdx.x;
  sS[h] = S[b * GH + h];
  __syncthreads();
  float acc = bf1[h];
#pragma unroll 8
  for (int k = 0; k < GH; ++k) acc += sS[k] * Wf1[k * GH + h];
  oS[h] = acc > 0.f ? acc : 0.f;
  __syncthreads();
  if (h < FOUT) {
    float o = bf2[h];
#pragma unroll 8
    for (int k = 0; k < GH; ++k) o += oS[k] * Wf2[k * FOUT + h];
    out[b * FOUT + h] = o;
  }
}

extern "C" void kernel_launch(void* const* d_in, const int* in_sizes, int n_in,
                              void* d_out, int out_size, void* d_ws, size_t ws_size,
                              hipStream_t stream) {
  const float* image    = (const float*)d_in[0];
  const float* question = (const float*)d_in[1];
  const float* Wg1      = (const float*)d_in[2];
  const float* bg1      = (const float*)d_in[3];
  const float* Wg2      = (const float*)d_in[4];
  const float* bg2      = (const float*)d_in[5];
  const float* Wf1      = (const float*)d_in[6];
  const float* bf1      = (const float*)d_in[7];
  const float* Wf2      = (const float*)d_in[8];
  const float* bf2      = (const float*)d_in[9];
  float* out = (float*)d_out;

  float* wsf  = (float*)d_ws;
  float* Lqp  = wsf + LQ_OFF;
  float* Rp   = wsf + R_OFF;
  float* Sp   = wsf + S_OFF;
  u16*   Bswz = (u16*)d_ws + BS_U16;

  prep<<<2 * NB * NN + 256, 256, 0, stream>>>(image, question, Wg1, bg1, Wg2,
                                              Lqp, Rp, Sp, Bswz);
  pair_gemm<<<NB * BPB, 256, 0, stream>>>(Lqp, Rp, Bswz, bg2, Sp);
  final_mlp<<<NB, 256, 0, stream>>>(Sp, Wf1, bf1, Wf2, bf2, out);
}